// Round 1
// baseline (488.899 us; speedup 1.0000x reference)
//
#include <hip/hip_runtime.h>
#include <hip/hip_bf16.h>
#include <math.h>

#define BATCH 8
#define SEQ   2048
#define EMB   1024
#define HEAD  64
#define BT    (BATCH * SEQ)

// =====================================================================
// Kernel 1: fused QKV projection (fp32).
// grid = BT/32 = 512 blocks, block = 256 threads (4 waves).
// Each block computes 32 rows x 192 outputs (q,k,v of 64 each).
// Wave w handles rows w*8 .. w*8+7; lane = output column h (0..63).
// X tile staged in LDS (broadcast reads); W streamed through L1/L2
// (working set 48KB/chunk, L2-resident).
// =====================================================================
__global__ __launch_bounds__(256) void qkv_proj(
    const float* __restrict__ X,
    const float* __restrict__ Wq,
    const float* __restrict__ Wk,
    const float* __restrict__ Wv,
    float* __restrict__ Q,
    float* __restrict__ K,
    float* __restrict__ V)
{
    __shared__ float xs[32][68];   // 32 rows x 64 e-chunk, pad 4 (272B rows, 16B aligned)

    const int tid  = threadIdx.x;
    const int lane = tid & 63;
    const int wv   = tid >> 6;     // wave id 0..3
    const int r0   = wv * 8;
    const int row0 = blockIdx.x * 32;

    float aq[8], ak[8], av[8];
#pragma unroll
    for (int j = 0; j < 8; ++j) { aq[j] = 0.f; ak[j] = 0.f; av[j] = 0.f; }

    for (int ec = 0; ec < EMB; ec += 64) {
        __syncthreads();
        // stage 32x64 X tile: 512 float4, 2 per thread, coalesced
        for (int i = tid; i < 512; i += 256) {
            const int r  = i >> 4;
            const int d4 = (i & 15) * 4;
            float4 x4 = *(const float4*)&X[(size_t)(row0 + r) * EMB + ec + d4];
            *(float4*)&xs[r][d4] = x4;
        }
        __syncthreads();

        for (int e0 = 0; e0 < 64; e0 += 4) {
            const int eg = (ec + e0) * HEAD + lane;
            const float wq0 = Wq[eg];            const float wk0 = Wk[eg];            const float wv0 = Wv[eg];
            const float wq1 = Wq[eg + HEAD];     const float wk1 = Wk[eg + HEAD];     const float wv1 = Wv[eg + HEAD];
            const float wq2 = Wq[eg + 2*HEAD];   const float wk2 = Wk[eg + 2*HEAD];   const float wv2 = Wv[eg + 2*HEAD];
            const float wq3 = Wq[eg + 3*HEAD];   const float wk3 = Wk[eg + 3*HEAD];   const float wv3 = Wv[eg + 3*HEAD];
#pragma unroll
            for (int j = 0; j < 8; ++j) {
                float4 xr = *(const float4*)&xs[r0 + j][e0];   // broadcast b128
                aq[j] += xr.x * wq0; aq[j] += xr.y * wq1; aq[j] += xr.z * wq2; aq[j] += xr.w * wq3;
                ak[j] += xr.x * wk0; ak[j] += xr.y * wk1; ak[j] += xr.z * wk2; ak[j] += xr.w * wk3;
                av[j] += xr.x * wv0; av[j] += xr.y * wv1; av[j] += xr.z * wv2; av[j] += xr.w * wv3;
            }
        }
    }

#pragma unroll
    for (int j = 0; j < 8; ++j) {
        const size_t orow = (size_t)(row0 + r0 + j) * HEAD + lane;
        Q[orow] = aq[j];
        K[orow] = ak[j];
        V[orow] = av[j];
    }
}

// =====================================================================
// Kernel 2: causal flash attention (fp32), head_size=64.
// grid = 8 batches * 32 tile-pairs = 256 blocks, block = 256 (4 waves).
// Block processes q-tile pair (i, 63-i) sequentially -> constant 33
// k-tile passes per block (causal load balance).
// Per wave: 8 q rows. Phase A (lane=k): scores; wave shfl_xor online
// softmax. Phase B (lane=d): PV accumulate.
// =====================================================================
__global__ __launch_bounds__(256) void attn_fwd(
    const float* __restrict__ Q,
    const float* __restrict__ K,
    const float* __restrict__ V,
    float* __restrict__ O)
{
    __shared__ float qsT[64][36];   // [d][r]   144B rows (16B aligned)
    __shared__ float ks [64][68];   // [k][d]   272B rows
    __shared__ float vs [64][68];   // [k][d]
    __shared__ float psT[32][68];   // [r][k]

    const int tid   = threadIdx.x;
    const int lane  = tid & 63;
    const int wv    = tid >> 6;
    const int r0    = wv * 8;
    const int b     = blockIdx.x >> 5;
    const int pairi = blockIdx.x & 31;
    const float scale = 0.125f;    // 1/sqrt(64)
    const size_t base = (size_t)b * SEQ * HEAD;

    for (int pass = 0; pass < 2; ++pass) {
        const int qt    = pass ? (63 - pairi) : pairi;
        const int qrow0 = qt * 32;

        __syncthreads();
        // stage Q tile transposed: [d][r]
        for (int i = tid; i < 512; i += 256) {
            const int r  = i >> 4;
            const int d4 = (i & 15) * 4;
            float4 q4 = *(const float4*)&Q[base + (size_t)(qrow0 + r) * HEAD + d4];
            qsT[d4 + 0][r] = q4.x;
            qsT[d4 + 1][r] = q4.y;
            qsT[d4 + 2][r] = q4.z;
            qsT[d4 + 3][r] = q4.w;
        }

        float m[8], l[8], acc[8];
#pragma unroll
        for (int j = 0; j < 8; ++j) { m[j] = -INFINITY; l[j] = 0.f; acc[j] = 0.f; }

        const int nkt = qt / 2 + 1;
        for (int kt = 0; kt < nkt; ++kt) {
            __syncthreads();
            // stage K,V tiles [64][64] (natural layout, coalesced float4)
            for (int i = tid; i < 1024; i += 256) {
                const int r  = i >> 4;
                const int d4 = (i & 15) * 4;
                const size_t g = base + (size_t)(kt * 64 + r) * HEAD + d4;
                *(float4*)&ks[r][d4] = *(const float4*)&K[g];
                *(float4*)&vs[r][d4] = *(const float4*)&V[g];
            }
            __syncthreads();

            // ---- Phase A: scores. lane = local k index. ----
            float s[8];
#pragma unroll
            for (int j = 0; j < 8; ++j) s[j] = 0.f;

            for (int d0 = 0; d0 < 64; d0 += 4) {
                float4 kq = *(const float4*)&ks[lane][d0];
                float kqa[4] = {kq.x, kq.y, kq.z, kq.w};
#pragma unroll
                for (int mm = 0; mm < 4; ++mm) {
                    const float kk = kqa[mm];
                    float4 qa = *(const float4*)&qsT[d0 + mm][r0];
                    float4 qb = *(const float4*)&qsT[d0 + mm][r0 + 4];
                    s[0] += qa.x * kk; s[1] += qa.y * kk; s[2] += qa.z * kk; s[3] += qa.w * kk;
                    s[4] += qb.x * kk; s[5] += qb.y * kk; s[6] += qb.z * kk; s[7] += qb.w * kk;
                }
            }

            // ---- online softmax (per row, reduce over 64 lanes) ----
            const int kglob = kt * 64 + lane;
            float corr[8];
#pragma unroll
            for (int j = 0; j < 8; ++j) {
                const int qglob = qrow0 + r0 + j;
                float sv = (kglob <= qglob) ? (s[j] * scale) : -INFINITY;
                float mx = sv;
#pragma unroll
                for (int off = 32; off >= 1; off >>= 1)
                    mx = fmaxf(mx, __shfl_xor(mx, off));
                const float mnew = fmaxf(m[j], mx);
                const float c = __expf(m[j] - mnew);     // first tile: exp(-inf)=0
                float p = __expf(sv - mnew);              // masked lanes: exp(-inf)=0
                float ps = p;
#pragma unroll
                for (int off = 32; off >= 1; off >>= 1)
                    ps += __shfl_xor(ps, off);
                l[j] = l[j] * c + ps;
                m[j] = mnew;
                corr[j] = c;
                psT[r0 + j][lane] = p;   // own-wave region; lgkm dependency handled by compiler
            }

#pragma unroll
            for (int j = 0; j < 8; ++j) acc[j] *= corr[j];

            // ---- Phase B: PV. lane = d index. ----
            for (int j0 = 0; j0 < 64; j0 += 4) {
                float4 p4[8];
#pragma unroll
                for (int r = 0; r < 8; ++r)
                    p4[r] = *(const float4*)&psT[r0 + r][j0];   // broadcast b128
                float pa[8][4];
#pragma unroll
                for (int r = 0; r < 8; ++r) {
                    pa[r][0] = p4[r].x; pa[r][1] = p4[r].y; pa[r][2] = p4[r].z; pa[r][3] = p4[r].w;
                }
#pragma unroll
                for (int jj = 0; jj < 4; ++jj) {
                    const float vv = vs[j0 + jj][lane];
#pragma unroll
                    for (int r = 0; r < 8; ++r)
                        acc[r] += pa[r][jj] * vv;
                }
            }
        }

        // epilogue: normalize and store (coalesced)
#pragma unroll
        for (int j = 0; j < 8; ++j) {
            O[base + (size_t)(qrow0 + r0 + j) * HEAD + lane] = acc[j] / l[j];
        }
    }
}

// =====================================================================
extern "C" void kernel_launch(void* const* d_in, const int* in_sizes, int n_in,
                              void* d_out, int out_size, void* d_ws, size_t ws_size,
                              hipStream_t stream)
{
    const float* X  = (const float*)d_in[0];
    const float* Wq = (const float*)d_in[1];
    const float* Wk = (const float*)d_in[2];
    const float* Wv = (const float*)d_in[3];
    float* O = (float*)d_out;

    // workspace: Q,K,V each BT*HEAD fp32 = 4MB -> 12MB total
    float* Q = (float*)d_ws;
    float* K = Q + (size_t)BT * HEAD;
    float* V = K + (size_t)BT * HEAD;

    qkv_proj<<<dim3(BT / 32), dim3(256), 0, stream>>>(X, Wq, Wk, Wv, Q, K, V);
    attn_fwd<<<dim3(BATCH * 32), dim3(256), 0, stream>>>(Q, K, V, O);
}

// Round 2
// 219.943 us; speedup vs baseline: 2.2228x; 2.2228x over previous
//
#include <hip/hip_runtime.h>
#include <hip/hip_bf16.h>
#include <math.h>

#define BATCH 8
#define SEQ   2048
#define EMB   1024
#define HEAD  64
#define BT    (BATCH * SEQ)

typedef __attribute__((ext_vector_type(8))) short  short8;
typedef __attribute__((ext_vector_type(4))) float  floatx4;

__device__ __forceinline__ unsigned short f2bf(float x) {
    union { __hip_bfloat16 h; unsigned short u; } cv;
    cv.h = __float2bfloat16(x);   // RNE
    return cv.u;
}

// =====================================================================
// Kernel 0: transpose+convert weights -> WT[192][1024] bf16.
// WT[c][k]: c in [0,64)=Wq col, [64,128)=Wk, [128,192)=Wv.
// grid = 3 weights x 16 k-chunks = 48 blocks x 256 thr.
// =====================================================================
__global__ __launch_bounds__(256) void wt_prep(
    const float* __restrict__ Wq, const float* __restrict__ Wk,
    const float* __restrict__ Wv, unsigned short* __restrict__ WT)
{
    __shared__ float tile[64][65];
    const int w  = blockIdx.x >> 4;        // 0..2
    const int k0 = (blockIdx.x & 15) * 64;
    const float* W = (w == 0) ? Wq : (w == 1) ? Wk : Wv;
    const int tid = threadIdx.x;

    for (int idx = tid; idx < 4096; idx += 256) {
        const int kr = idx >> 6, n = idx & 63;       // coalesced over n
        tile[kr][n] = W[(size_t)(k0 + kr) * HEAD + n];
    }
    __syncthreads();
    const int n  = tid >> 2;
    const int j0 = (tid & 3) * 16;
    unsigned short* dst = WT + (size_t)(w * 64 + n) * EMB + k0 + j0;
#pragma unroll
    for (int j = 0; j < 16; ++j) dst[j] = f2bf(tile[j0 + j][n]);
}

// =====================================================================
// Kernel 1: QKV projection via bf16 MFMA 16x16x32. No LDS.
// grid = BT/32 = 512 blocks x 256 thr (4 waves, 2x2).
// Wave (wm,wn): rows blockIdx*32 + wm*16 .. +15, cols wn*96 .. +95 (6 n-tiles).
// A-frag: X fp32 loaded per-lane (row = lane&15, k = (lane>>4)*8+j), cvt bf16.
// B-frag: WT bf16 direct (col = lane&15, same k grouping). L1/L2 resident.
// Outputs: Q,K natural [t][64] bf16; V transposed VT[b][64][2048] bf16.
// =====================================================================
__global__ __launch_bounds__(256) void qkv_mfma(
    const float* __restrict__ X, const unsigned short* __restrict__ WT,
    unsigned short* __restrict__ Q, unsigned short* __restrict__ K,
    unsigned short* __restrict__ VT)
{
    const int tid = threadIdx.x;
    const int l   = tid & 63;
    const int wv  = tid >> 6;
    const int wm  = wv >> 1, wn = wv & 1;
    const int g   = l >> 4,  q  = l & 15;
    const int arow = blockIdx.x * 32 + wm * 16 + q;

    floatx4 acc[6];
#pragma unroll
    for (int nt = 0; nt < 6; ++nt) acc[nt] = (floatx4){0.f, 0.f, 0.f, 0.f};

    const float*          xp = X  + (size_t)arow * EMB + g * 8;
    const unsigned short* wp = WT + (size_t)(wn * 96 + q) * EMB + g * 8;

    for (int k0 = 0; k0 < EMB; k0 += 32) {
        const float4 xa = *(const float4*)(xp);
        const float4 xb = *(const float4*)(xp + 4);
        xp += 32;
        short8 a;
        a[0] = (short)f2bf(xa.x); a[1] = (short)f2bf(xa.y);
        a[2] = (short)f2bf(xa.z); a[3] = (short)f2bf(xa.w);
        a[4] = (short)f2bf(xb.x); a[5] = (short)f2bf(xb.y);
        a[6] = (short)f2bf(xb.z); a[7] = (short)f2bf(xb.w);
#pragma unroll
        for (int nt = 0; nt < 6; ++nt) {
            const short8 bb = *(const short8*)(wp + (size_t)nt * 16 * EMB);
            acc[nt] = __builtin_amdgcn_mfma_f32_16x16x32_bf16(a, bb, acc[nt], 0, 0, 0);
        }
        wp += 32;
    }

    // C/D layout: col = lane&15 (=q), row = (lane>>4)*4 + r.
    const int trow0 = blockIdx.x * 32 + wm * 16 + g * 4;
#pragma unroll
    for (int nt = 0; nt < 6; ++nt) {
        const int c = wn * 96 + nt * 16 + q;
#pragma unroll
        for (int r = 0; r < 4; ++r) {
            const unsigned short v = f2bf(acc[nt][r]);
            const int t = trow0 + r;
            if (c < 64) {
                Q[(size_t)t * HEAD + c] = v;
            } else if (c < 128) {
                K[(size_t)t * HEAD + (c - 64)] = v;
            } else {
                const int bb = t >> 11, tl = t & (SEQ - 1);
                VT[((size_t)bb * HEAD + (c - 128)) * SEQ + tl] = v;
            }
        }
    }
}

// =====================================================================
// Kernel 2: causal flash attention via bf16 MFMA.
// grid = 64 q-tiles x 8 batches = 512 blocks x 128 thr (2 waves x 16 q-rows).
// S^T = mfma(A=K-tile, B=Q^T): both frags natural row-major, no transposes.
// lane holds S^T at (kk = t*16+g*4+r, q = lane&15); softmax reduce =
// in-lane over 16 vals + shfl_xor(16,32). P -> padded LDS -> PV A-frag.
// PV B-frag reads pre-transposed Vs[d][kk] (staged from global VT).
// =====================================================================
__global__ __launch_bounds__(128) void attn_mfma(
    const unsigned short* __restrict__ Q, const unsigned short* __restrict__ K,
    const unsigned short* __restrict__ VT, float* __restrict__ O)
{
    __shared__ unsigned short Ks[64][72];   // K tile [kk][d], 144B rows
    __shared__ unsigned short Vs[64][72];   // V^T tile [d][kk]
    __shared__ unsigned short Ps[32][72];   // P [q_local][kk]

    const int tid = threadIdx.x;
    const int l   = tid & 63;
    const int wv  = tid >> 6;               // 0,1
    const int g   = l >> 4, q = l & 15;
    const int qt  = 63 - (blockIdx.x >> 3); // largest-work blocks first
    const int b   = blockIdx.x & 7;
    const int qrow0 = qt * 32 + wv * 16;
    const size_t kbase = (size_t)b * SEQ * HEAD;
    const size_t vbase = (size_t)b * HEAD * SEQ;

    // Q^T B-frags: col=q, k=d=(dc*32 + g*8 + j). Held in regs for all tiles.
    short8 bq[2];
#pragma unroll
    for (int dc = 0; dc < 2; ++dc)
        bq[dc] = *(const short8*)&Q[kbase + (size_t)(qrow0 + q) * HEAD + dc * 32 + g * 8];

    floatx4 o[4];
#pragma unroll
    for (int dt = 0; dt < 4; ++dt) o[dt] = (floatx4){0.f, 0.f, 0.f, 0.f};
    float m_run = -INFINITY, l_run = 0.f;

    const int nkt = (qt >> 1) + 1;
    for (int kt = 0; kt < nkt; ++kt) {
        __syncthreads();   // previous tile fully consumed
        for (int c = tid; c < 512; c += 128) {
            const int r = c >> 3, k8 = (c & 7) * 8;
            *(short8*)&Ks[r][k8] = *(const short8*)&K[kbase + (size_t)(kt * 64 + r) * HEAD + k8];
            *(short8*)&Vs[r][k8] = *(const short8*)&VT[vbase + (size_t)r * SEQ + kt * 64 + k8];
        }
        __syncthreads();

        // ---- S^T: 4 kk-tiles x 2 d-chunks ----
        floatx4 s[4];
#pragma unroll
        for (int t = 0; t < 4; ++t) {
            s[t] = (floatx4){0.f, 0.f, 0.f, 0.f};
#pragma unroll
            for (int dc = 0; dc < 2; ++dc) {
                const short8 ak = *(const short8*)&Ks[t * 16 + q][dc * 32 + g * 8];
                s[t] = __builtin_amdgcn_mfma_f32_16x16x32_bf16(ak, bq[dc], s[t], 0, 0, 0);
            }
        }

        // ---- scale + causal mask (diag tile only) ----
        float sv[4][4];
        if (kt == nkt - 1) {
#pragma unroll
            for (int t = 0; t < 4; ++t)
#pragma unroll
                for (int r = 0; r < 4; ++r) {
                    const int kg = kt * 64 + t * 16 + g * 4 + r;
                    sv[t][r] = (kg > qrow0 + q) ? -INFINITY : s[t][r] * 0.125f;
                }
        } else {
#pragma unroll
            for (int t = 0; t < 4; ++t)
#pragma unroll
                for (int r = 0; r < 4; ++r) sv[t][r] = s[t][r] * 0.125f;
        }

        // ---- online softmax (row = q, spread over 4 g-lanes) ----
        float pm = -INFINITY;
#pragma unroll
        for (int t = 0; t < 4; ++t)
#pragma unroll
            for (int r = 0; r < 4; ++r) pm = fmaxf(pm, sv[t][r]);
        pm = fmaxf(pm, __shfl_xor(pm, 16));
        pm = fmaxf(pm, __shfl_xor(pm, 32));
        const float mnew = fmaxf(m_run, pm);
        const float crow = __expf(m_run - mnew);   // first tile: exp(-inf)=0
        float p[4][4];
        float psum = 0.f;
#pragma unroll
        for (int t = 0; t < 4; ++t)
#pragma unroll
            for (int r = 0; r < 4; ++r) {
                p[t][r] = __expf(sv[t][r] - mnew);
                psum += p[t][r];
            }
        psum += __shfl_xor(psum, 16);
        psum += __shfl_xor(psum, 32);
        l_run = l_run * crow + psum;
        m_run = mnew;

        // rescale O: lane holds O rows q' = g*4+r; fetch crow from lane q'.
#pragma unroll
        for (int r = 0; r < 4; ++r) {
            const float cr = __shfl(crow, g * 4 + r);
#pragma unroll
            for (int dt = 0; dt < 4; ++dt) o[dt][r] *= cr;
        }

        // ---- P -> LDS (bf16, packed pairs) ----
#pragma unroll
        for (int t = 0; t < 4; ++t) {
            const unsigned int lo = (unsigned)f2bf(p[t][0]) | ((unsigned)f2bf(p[t][1]) << 16);
            const unsigned int hi = (unsigned)f2bf(p[t][2]) | ((unsigned)f2bf(p[t][3]) << 16);
            *(unsigned int*)&Ps[wv * 16 + q][t * 16 + g * 4]     = lo;
            *(unsigned int*)&Ps[wv * 16 + q][t * 16 + g * 4 + 2] = hi;
        }
        // wave-local write->read fence (cross-lane via LDS, same wave)
        asm volatile("s_waitcnt lgkmcnt(0)" ::: "memory");
        __builtin_amdgcn_sched_barrier(0);

        // ---- PV: O[q][d] += P[q][kk] * V[kk][d] ----
#pragma unroll
        for (int kc = 0; kc < 2; ++kc) {
            const short8 pa = *(const short8*)&Ps[wv * 16 + q][kc * 32 + g * 8];
#pragma unroll
            for (int dt = 0; dt < 4; ++dt) {
                const short8 vb = *(const short8*)&Vs[dt * 16 + q][kc * 32 + g * 8];
                o[dt] = __builtin_amdgcn_mfma_f32_16x16x32_bf16(pa, vb, o[dt], 0, 0, 0);
            }
        }
    }

    // ---- epilogue: normalize, store fp32 ----
    float lr[4];
#pragma unroll
    for (int r = 0; r < 4; ++r) lr[r] = __shfl(l_run, g * 4 + r);
    const size_t obase = (size_t)b * SEQ * HEAD;
#pragma unroll
    for (int dt = 0; dt < 4; ++dt)
#pragma unroll
        for (int r = 0; r < 4; ++r)
            O[obase + (size_t)(qrow0 + g * 4 + r) * HEAD + dt * 16 + q] = o[dt][r] / lr[r];
}

// =====================================================================
extern "C" void kernel_launch(void* const* d_in, const int* in_sizes, int n_in,
                              void* d_out, int out_size, void* d_ws, size_t ws_size,
                              hipStream_t stream)
{
    const float* X  = (const float*)d_in[0];
    const float* Wq = (const float*)d_in[1];
    const float* Wk = (const float*)d_in[2];
    const float* Wv = (const float*)d_in[3];
    float* O = (float*)d_out;

    unsigned short* Qb = (unsigned short*)d_ws;              // [BT][64] bf16
    unsigned short* Kb = Qb + (size_t)BT * HEAD;             // [BT][64]
    unsigned short* Vt = Kb + (size_t)BT * HEAD;             // [B][64][2048]
    unsigned short* WT = Vt + (size_t)BT * HEAD;             // [192][1024]

    wt_prep <<<dim3(48),  dim3(256), 0, stream>>>(Wq, Wk, Wv, WT);
    qkv_mfma<<<dim3(512), dim3(256), 0, stream>>>(X, WT, Qb, Kb, Vt);
    attn_mfma<<<dim3(512), dim3(128), 0, stream>>>(Qb, Kb, Vt, O);
}

// Round 3
// 188.192 us; speedup vs baseline: 2.5979x; 1.1687x over previous
//
#include <hip/hip_runtime.h>
#include <hip/hip_bf16.h>
#include <math.h>

#define BATCH 8
#define SEQ   2048
#define EMB   1024
#define HEAD  64
#define BT    (BATCH * SEQ)

typedef __attribute__((ext_vector_type(8))) short  short8;
typedef __attribute__((ext_vector_type(4))) float  floatx4;

__device__ __forceinline__ unsigned short f2bf(float x) {
    union { __hip_bfloat16 h; unsigned short u; } cv;
    cv.h = __float2bfloat16(x);   // RNE
    return cv.u;
}

// =====================================================================
// Kernel 0: transpose+convert weights -> WT[192][1024] bf16.
// WT[c][k]: c in [0,64)=Wq col, [64,128)=Wk, [128,192)=Wv.
// grid = 3 weights x 16 k-chunks = 48 blocks x 256 thr.
// Vectorized 16B stores (4 threads per output row -> 128B segments).
// =====================================================================
__global__ __launch_bounds__(256) void wt_prep(
    const float* __restrict__ Wq, const float* __restrict__ Wk,
    const float* __restrict__ Wv, unsigned short* __restrict__ WT)
{
    __shared__ float tile[64][65];
    const int w  = blockIdx.x >> 4;        // 0..2
    const int k0 = (blockIdx.x & 15) * 64;
    const float* W = (w == 0) ? Wq : (w == 1) ? Wk : Wv;
    const int tid = threadIdx.x;

    for (int idx = tid; idx < 4096; idx += 256) {
        const int kr = idx >> 6, n = idx & 63;       // coalesced over n
        tile[kr][n] = W[(size_t)(k0 + kr) * HEAD + n];
    }
    __syncthreads();
    const int n  = tid >> 2;
    const int k8 = (tid & 3) * 16;
    unsigned short* dst = WT + (size_t)(w * 64 + n) * EMB + k0 + k8;
    short8 v0, v1;
#pragma unroll
    for (int j = 0; j < 8; ++j) v0[j] = (short)f2bf(tile[k8 + j][n]);
#pragma unroll
    for (int j = 0; j < 8; ++j) v1[j] = (short)f2bf(tile[k8 + 8 + j][n]);
    *(short8*)(dst)     = v0;
    *(short8*)(dst + 8) = v1;
}

// =====================================================================
// Kernel 1: QKV projection via bf16 MFMA 16x16x32, 2-stage reg pipeline.
// grid = BT/32 = 512 blocks x 256 thr (4 waves, 2x2).
// Wave (wm,wn): rows blockIdx*32 + wm*16..+15, cols wn*96..+95 (6 n-tiles).
// Loads for k0+32 issued while converting/MFMA-ing k0 (latency hidden).
// Outputs: Q,K natural [t][64] bf16; V transposed VT[b][64][2048] bf16.
// =====================================================================
__global__ __launch_bounds__(256) void qkv_mfma(
    const float* __restrict__ X, const unsigned short* __restrict__ WT,
    unsigned short* __restrict__ Q, unsigned short* __restrict__ K,
    unsigned short* __restrict__ VT)
{
    const int tid = threadIdx.x;
    const int l   = tid & 63;
    const int wv  = tid >> 6;
    const int wm  = wv >> 1, wn = wv & 1;
    const int g   = l >> 4,  q  = l & 15;
    const int arow = blockIdx.x * 32 + wm * 16 + q;

    floatx4 acc[6];
#pragma unroll
    for (int nt = 0; nt < 6; ++nt) acc[nt] = (floatx4){0.f, 0.f, 0.f, 0.f};

    const float*          xp = X  + (size_t)arow * EMB + g * 8;
    const unsigned short* wp = WT + (size_t)(wn * 96 + q) * EMB + g * 8;

    // prologue: load chunk 0
    float4 xa = *(const float4*)(xp);
    float4 xb = *(const float4*)(xp + 4);
    short8 w[6];
#pragma unroll
    for (int nt = 0; nt < 6; ++nt) w[nt] = *(const short8*)(wp + (size_t)nt * 16 * EMB);

    for (int k0 = 0; k0 < EMB - 32; k0 += 32) {
        // issue next-chunk loads
        float4 xa2 = *(const float4*)(xp + 32);
        float4 xb2 = *(const float4*)(xp + 36);
        short8 w2[6];
#pragma unroll
        for (int nt = 0; nt < 6; ++nt) w2[nt] = *(const short8*)(wp + 32 + (size_t)nt * 16 * EMB);
        xp += 32; wp += 32;

        // compute current chunk
        short8 a;
        a[0] = (short)f2bf(xa.x); a[1] = (short)f2bf(xa.y);
        a[2] = (short)f2bf(xa.z); a[3] = (short)f2bf(xa.w);
        a[4] = (short)f2bf(xb.x); a[5] = (short)f2bf(xb.y);
        a[6] = (short)f2bf(xb.z); a[7] = (short)f2bf(xb.w);
#pragma unroll
        for (int nt = 0; nt < 6; ++nt)
            acc[nt] = __builtin_amdgcn_mfma_f32_16x16x32_bf16(a, w[nt], acc[nt], 0, 0, 0);

        // rotate
        xa = xa2; xb = xb2;
#pragma unroll
        for (int nt = 0; nt < 6; ++nt) w[nt] = w2[nt];
    }
    // final chunk
    {
        short8 a;
        a[0] = (short)f2bf(xa.x); a[1] = (short)f2bf(xa.y);
        a[2] = (short)f2bf(xa.z); a[3] = (short)f2bf(xa.w);
        a[4] = (short)f2bf(xb.x); a[5] = (short)f2bf(xb.y);
        a[6] = (short)f2bf(xb.z); a[7] = (short)f2bf(xb.w);
#pragma unroll
        for (int nt = 0; nt < 6; ++nt)
            acc[nt] = __builtin_amdgcn_mfma_f32_16x16x32_bf16(a, w[nt], acc[nt], 0, 0, 0);
    }

    // C/D layout: col = lane&15 (=q), row = (lane>>4)*4 + r.
    const int trow0 = blockIdx.x * 32 + wm * 16 + g * 4;
#pragma unroll
    for (int nt = 0; nt < 6; ++nt) {
        const int c = wn * 96 + nt * 16 + q;
#pragma unroll
        for (int r = 0; r < 4; ++r) {
            const unsigned short v = f2bf(acc[nt][r]);
            const int t = trow0 + r;
            if (c < 64) {
                Q[(size_t)t * HEAD + c] = v;
            } else if (c < 128) {
                K[(size_t)t * HEAD + (c - 64)] = v;
            } else {
                const int bb = t >> 11, tl = t & (SEQ - 1);
                VT[((size_t)bb * HEAD + (c - 128)) * SEQ + tl] = v;
            }
        }
    }
}

// =====================================================================
// Kernel 2: causal flash attention via bf16 MFMA, pipelined.
// grid = 64 q-tiles x 8 batches = 512 blocks x 128 thr (2 waves x 16 rows).
// Per k-tile: ds_write(prefetched regs) -> barrier -> issue next-tile
// global loads -> compute. Double-buffered K/V LDS; one barrier/tile.
// Prefetch issue AFTER the barrier (barrier drains vmcnt!).
// =====================================================================
__global__ __launch_bounds__(128) void attn_mfma(
    const unsigned short* __restrict__ Q, const unsigned short* __restrict__ K,
    const unsigned short* __restrict__ VT, float* __restrict__ O)
{
    __shared__ unsigned short Ks[2][64][72];   // [buf][kk][d]
    __shared__ unsigned short Vs[2][64][72];   // [buf][d][kk]
    __shared__ unsigned short Ps[32][72];      // [q_local][kk]

    const int tid = threadIdx.x;
    const int l   = tid & 63;
    const int wv  = tid >> 6;               // 0,1
    const int g   = l >> 4, q = l & 15;
    const int qt  = 63 - (blockIdx.x >> 3); // largest-work blocks first
    const int b   = blockIdx.x & 7;
    const int qrow0 = qt * 32 + wv * 16;
    const size_t kbase = (size_t)b * SEQ * HEAD;
    const size_t vbase = (size_t)b * HEAD * SEQ;

    // Q^T B-frags: col=q, k=d=(dc*32 + g*8 + j). Held in regs for all tiles.
    short8 bq[2];
#pragma unroll
    for (int dc = 0; dc < 2; ++dc)
        bq[dc] = *(const short8*)&Q[kbase + (size_t)(qrow0 + q) * HEAD + dc * 32 + g * 8];

    floatx4 o[4];
#pragma unroll
    for (int dt = 0; dt < 4; ++dt) o[dt] = (floatx4){0.f, 0.f, 0.f, 0.f};
    float m_run = -INFINITY, l_run = 0.f;

    const int nkt = (qt >> 1) + 1;

    // prologue: prefetch tile 0 into regs
    short8 kreg[4], vreg[4];
#pragma unroll
    for (int i = 0; i < 4; ++i) {
        const int c = tid + i * 128, r = c >> 3, k8 = (c & 7) * 8;
        kreg[i] = *(const short8*)&K [kbase + (size_t)r * HEAD + k8];
        vreg[i] = *(const short8*)&VT[vbase + (size_t)r * SEQ  + k8];
    }

    for (int kt = 0; kt < nkt; ++kt) {
        const int bs = kt & 1;
        // stage prefetched regs -> LDS (compiler inserts vmcnt wait here)
#pragma unroll
        for (int i = 0; i < 4; ++i) {
            const int c = tid + i * 128, r = c >> 3, k8 = (c & 7) * 8;
            *(short8*)&Ks[bs][r][k8] = kreg[i];
            *(short8*)&Vs[bs][r][k8] = vreg[i];
        }
        __syncthreads();

        // issue next-tile loads; latency hides under compute below
        if (kt + 1 < nkt) {
#pragma unroll
            for (int i = 0; i < 4; ++i) {
                const int c = tid + i * 128, r = c >> 3, k8 = (c & 7) * 8;
                kreg[i] = *(const short8*)&K [kbase + (size_t)((kt + 1) * 64 + r) * HEAD + k8];
                vreg[i] = *(const short8*)&VT[vbase + (size_t)r * SEQ + (kt + 1) * 64 + k8];
            }
        }

        // ---- S^T: 4 kk-tiles x 2 d-chunks ----
        floatx4 s[4];
#pragma unroll
        for (int t = 0; t < 4; ++t) {
            s[t] = (floatx4){0.f, 0.f, 0.f, 0.f};
#pragma unroll
            for (int dc = 0; dc < 2; ++dc) {
                const short8 ak = *(const short8*)&Ks[bs][t * 16 + q][dc * 32 + g * 8];
                s[t] = __builtin_amdgcn_mfma_f32_16x16x32_bf16(ak, bq[dc], s[t], 0, 0, 0);
            }
        }

        // ---- scale + causal mask (diag tile only) ----
        float sv[4][4];
        if (kt == nkt - 1) {
#pragma unroll
            for (int t = 0; t < 4; ++t)
#pragma unroll
                for (int r = 0; r < 4; ++r) {
                    const int kg = kt * 64 + t * 16 + g * 4 + r;
                    sv[t][r] = (kg > qrow0 + q) ? -INFINITY : s[t][r] * 0.125f;
                }
        } else {
#pragma unroll
            for (int t = 0; t < 4; ++t)
#pragma unroll
                for (int r = 0; r < 4; ++r) sv[t][r] = s[t][r] * 0.125f;
        }

        // ---- online softmax (row = q, spread over 4 g-lanes) ----
        float pm = -INFINITY;
#pragma unroll
        for (int t = 0; t < 4; ++t)
#pragma unroll
            for (int r = 0; r < 4; ++r) pm = fmaxf(pm, sv[t][r]);
        pm = fmaxf(pm, __shfl_xor(pm, 16));
        pm = fmaxf(pm, __shfl_xor(pm, 32));
        const float mnew = fmaxf(m_run, pm);
        const float crow = __expf(m_run - mnew);   // first tile: exp(-inf)=0
        float p[4][4];
        float psum = 0.f;
#pragma unroll
        for (int t = 0; t < 4; ++t)
#pragma unroll
            for (int r = 0; r < 4; ++r) {
                p[t][r] = __expf(sv[t][r] - mnew);
                psum += p[t][r];
            }
        psum += __shfl_xor(psum, 16);
        psum += __shfl_xor(psum, 32);
        l_run = l_run * crow + psum;
        m_run = mnew;

        // rescale O: lane holds O rows q' = g*4+r; fetch crow from lane q'.
#pragma unroll
        for (int r = 0; r < 4; ++r) {
            const float cr = __shfl(crow, g * 4 + r);
#pragma unroll
            for (int dt = 0; dt < 4; ++dt) o[dt][r] *= cr;
        }

        // ---- P -> LDS (bf16, packed pairs) ----
#pragma unroll
        for (int t = 0; t < 4; ++t) {
            const unsigned int lo = (unsigned)f2bf(p[t][0]) | ((unsigned)f2bf(p[t][1]) << 16);
            const unsigned int hi = (unsigned)f2bf(p[t][2]) | ((unsigned)f2bf(p[t][3]) << 16);
            *(unsigned int*)&Ps[wv * 16 + q][t * 16 + g * 4]     = lo;
            *(unsigned int*)&Ps[wv * 16 + q][t * 16 + g * 4 + 2] = hi;
        }
        // wave-local write->read fence (cross-lane via LDS, same wave)
        asm volatile("s_waitcnt lgkmcnt(0)" ::: "memory");
        __builtin_amdgcn_sched_barrier(0);

        // ---- PV: O[q][d] += P[q][kk] * V[kk][d] ----
#pragma unroll
        for (int kc = 0; kc < 2; ++kc) {
            const short8 pa = *(const short8*)&Ps[wv * 16 + q][kc * 32 + g * 8];
#pragma unroll
            for (int dt = 0; dt < 4; ++dt) {
                const short8 vb = *(const short8*)&Vs[bs][dt * 16 + q][kc * 32 + g * 8];
                o[dt] = __builtin_amdgcn_mfma_f32_16x16x32_bf16(pa, vb, o[dt], 0, 0, 0);
            }
        }
    }

    // ---- epilogue: normalize, store fp32 ----
    float lr[4];
#pragma unroll
    for (int r = 0; r < 4; ++r) lr[r] = __shfl(l_run, g * 4 + r);
    const size_t obase = (size_t)b * SEQ * HEAD;
#pragma unroll
    for (int dt = 0; dt < 4; ++dt)
#pragma unroll
        for (int r = 0; r < 4; ++r)
            O[obase + (size_t)(qrow0 + g * 4 + r) * HEAD + dt * 16 + q] = o[dt][r] / lr[r];
}

// =====================================================================
extern "C" void kernel_launch(void* const* d_in, const int* in_sizes, int n_in,
                              void* d_out, int out_size, void* d_ws, size_t ws_size,
                              hipStream_t stream)
{
    const float* X  = (const float*)d_in[0];
    const float* Wq = (const float*)d_in[1];
    const float* Wk = (const float*)d_in[2];
    const float* Wv = (const float*)d_in[3];
    float* O = (float*)d_out;

    unsigned short* Qb = (unsigned short*)d_ws;              // [BT][64] bf16
    unsigned short* Kb = Qb + (size_t)BT * HEAD;             // [BT][64]
    unsigned short* Vt = Kb + (size_t)BT * HEAD;             // [B][64][2048]
    unsigned short* WT = Vt + (size_t)BT * HEAD;             // [192][1024]

    wt_prep <<<dim3(48),  dim3(256), 0, stream>>>(Wq, Wk, Wv, WT);
    qkv_mfma<<<dim3(512), dim3(256), 0, stream>>>(X, WT, Qb, Kb, Vt);
    attn_mfma<<<dim3(512), dim3(128), 0, stream>>>(Qb, Kb, Vt, O);
}